// Round 2
// 3159.809 us; speedup vs baseline: 1.1919x; 1.1919x over previous
//
#include <hip/hip_runtime.h>
#include <stdint.h>
#include <math.h>

// ---------------------------------------------------------------------------
// MLGKA layer forward, MI355X (gfx950).
// R6 == R5 resubmit (R5 bench died at container level; hazard audit found no
// kernel-induced fault path — see round notes). Structure:
// All bf16 GEMMs (W_o, FFN) use the 256^2 8-phase schedule (m201-style):
// BK=64, 8 waves / 512 threads, 128KiB dbuf LDS, st_16x32 XOR swizzle staged
// via inverse-swizzled global source (global_load_lds writes linearly),
// counted vmcnt(6/5) at K-tile boundaries only, raw s_barrier + sched_barrier
// fences, setprio(1) around MFMA clusters, bijective XCD blockIdx swizzle.
// Down-proj uses a BN=128 variant so its grid is 256 blocks (1/CU).
// Attention num/den path unchanged (full f32). Workspace: 232 MiB.
// ---------------------------------------------------------------------------

typedef __bf16 bf16x8 __attribute__((ext_vector_type(8)));
typedef float f32x4 __attribute__((ext_vector_type(4)));
typedef float f32x2 __attribute__((ext_vector_type(2)));
typedef unsigned short u16x8 __attribute__((ext_vector_type(8)));
typedef unsigned short u16x4 __attribute__((ext_vector_type(4)));

#define DEV __device__ __forceinline__

DEV unsigned short f2b(float f) {
  union { float f; unsigned int u; } v;
  v.f = f;
  unsigned int u = v.u;
  return (unsigned short)((u + 0x7FFFu + ((u >> 16) & 1u)) >> 16);  // RNE
}
DEV float b2f(unsigned short h) {
  union { unsigned int u; float f; } v;
  v.u = ((unsigned int)h) << 16;
  return v.f;
}

DEV void async16(const void* g, void* l) {
  typedef __attribute__((address_space(1))) unsigned int* gp_t;
  typedef __attribute__((address_space(3))) unsigned int* lp_t;
  __builtin_amdgcn_global_load_lds((gp_t)(g), (lp_t)(l), 16, 0, 0);
}

#define SCHED0() __builtin_amdgcn_sched_barrier(0)
#define BARRIER() do { SCHED0(); __builtin_amdgcn_s_barrier(); SCHED0(); } while (0)
#define LGKM0() do { asm volatile("s_waitcnt lgkmcnt(0)" ::: "memory"); SCHED0(); } while (0)

// ---------------------------------------------------------------------------
// 8-phase GEMM core: C[256 x BN] = A[256 x K] * Bt[BN x K]^T, bf16 MFMA.
// 8 waves (2M x 4N), BK=64; per-wave output 128 x BN/4.
// LDS regions per buffer: A_q0 | A_q1 (16KB each) | B_q0 | B_q1 (BN*64 B each).
// A_q{qa} holds rows with bit6==qa (storage row = (r>>7)*64 | (r&63)).
// B_q{qb} holds Bt-rows with (n mod CW)/QBS==qb (storage row = (n/CW)*QBS | n%QBS).
// st_16x32 swizzle: byte ^= ((byte>>9)&1)<<5 within each region; applied on
// ds_read addresses and inverted on the global staging source (LDS dest is
// linear as global_load_lds requires).
// Stage schedule (steady-state boundary queue = 14, vmcnt(6) drains all of
// tile t+1, leaves tile t+2's three prefetched regions in flight):
//   t.p0: B_q0(t+1) | t.p1: A_q0(t+2) | t.p2: B_q1(t+2) | t.p3: A_q1(t+2)
// WAR safety: each stage into region R is issued after the barrier following
// the last read of R's previous contents (verified per-phase, both buffers).
// ---------------------------------------------------------------------------
template <int BN, typename Epi>
DEV void gemm8p(const unsigned short* __restrict__ A,
                const unsigned short* __restrict__ Bt,
                int K, int lda, int ldb, Epi epi) {
  constexpr int CW = BN / 4;        // cols per wave (64 or 32)
  constexpr int JT = CW / 32;       // col-tiles per B-quadrant (2 or 1)
  constexpr int QBS = CW / 2;       // cols per B-quadrant per wave (32 or 16)
  constexpr int SZB = BN * 64;      // B region bytes (16384 or 8192)
  constexpr int BUFB = 2 * 16384 + 2 * SZB;
  constexpr int LB = BN / 128;      // B loads per thread per region (2 or 1)
  constexpr int VMC = 4 + LB;       // steady-state boundary vmcnt (6 or 5)
  __shared__ alignas(16) char lds[2 * BUFB];

  const int tid = threadIdx.x;
  const int lane = tid & 63;
  const int wave = tid >> 6;
  const int wm = wave >> 2, wn = wave & 3;
  const int ln = lane & 15;
  const int kq2 = ((lane >> 4) & 3) << 4;  // frag byte offset within 64B half-row

  // staging source descriptors (swizzle-inverted, per-thread constants)
  int srA[2], kbA[2], srB[2], kbB[2];
#pragma unroll
  for (int p = 0; p < 2; ++p) {
    int o = (p * 512 + tid) * 16;
    int x = o ^ (((o >> 9) & 1) << 5);
    srA[p] = x >> 7; kbA[p] = (x & 127) >> 1;
  }
#pragma unroll
  for (int p = 0; p < LB; ++p) {
    int o = (p * 512 + tid) * 16;
    int x = o ^ (((o >> 9) & 1) << 5);
    srB[p] = x >> 7; kbB[p] = (x & 127) >> 1;
  }

  const int NT = K >> 6;

  auto stageA = [&](int T, int qa) {
    char* dst = lds + (T & 1) * BUFB + qa * 16384;
    const unsigned short* src = A + T * 64;
#pragma unroll
    for (int p = 0; p < 2; ++p) {
      int r = ((srA[p] >> 6) << 7) | (qa << 6) | (srA[p] & 63);
      async16(src + (size_t)r * lda + kbA[p], dst + (p * 512 + tid) * 16);
    }
  };
  auto stageB = [&](int T, int qb) {
    char* dst = lds + (T & 1) * BUFB + 32768 + qb * SZB;
    const unsigned short* src = Bt + T * 64;
#pragma unroll
    for (int p = 0; p < LB; ++p) {
      int n = (srB[p] / QBS) * CW + qb * QBS + (srB[p] % QBS);
      async16(src + (size_t)n * ldb + kbB[p], dst + (p * 512 + tid) * 16);
    }
  };

  bf16x8 av[4][2], bv[JT][2];
  auto readA = [&](int b, int qa) {
#pragma unroll
    for (int i = 0; i < 4; ++i) {
      int sr = wm * 64 + i * 16 + ln;
      const char* rp = lds + b * BUFB + qa * 16384 + sr * 128;
      int sw = (sr & 4) << 3;
      av[i][0] = *(const bf16x8*)(rp + (kq2 ^ sw));
      av[i][1] = *(const bf16x8*)(rp + ((64 + kq2) ^ sw));
    }
  };
  auto readB = [&](int b, int qb) {
#pragma unroll
    for (int j = 0; j < JT; ++j) {
      int sr = wn * QBS + j * 16 + ln;
      const char* rp = lds + b * BUFB + 32768 + qb * SZB + sr * 128;
      int sw = (sr & 4) << 3;
      bv[j][0] = *(const bf16x8*)(rp + (kq2 ^ sw));
      bv[j][1] = *(const bf16x8*)(rp + ((64 + kq2) ^ sw));
    }
  };

  f32x4 acc[8][2 * JT];
  const f32x4 fz = {0.f, 0.f, 0.f, 0.f};
#pragma unroll
  for (int i = 0; i < 8; ++i)
#pragma unroll
    for (int j = 0; j < 2 * JT; ++j) acc[i][j] = fz;

  auto mf = [&](int qa, int qb) {
#pragma unroll
    for (int tt = 0; tt < 2; ++tt)
#pragma unroll
      for (int i = 0; i < 4; ++i)
#pragma unroll
        for (int j = 0; j < JT; ++j)
          acc[qa * 4 + i][qb * JT + j] = __builtin_amdgcn_mfma_f32_16x16x32_bf16(
              av[i][tt], bv[j][tt], acc[qa * 4 + i][qb * JT + j], 0, 0, 0);
  };

  auto vwait_steady = [&]() {
    if constexpr (VMC == 6) asm volatile("s_waitcnt vmcnt(6)" ::: "memory");
    else                    asm volatile("s_waitcnt vmcnt(5)" ::: "memory");
  };

  // prologue: tile0 fully + tile1 {A_q0, B_q1, A_q1}
  stageA(0, 0); stageB(0, 0); stageB(0, 1); stageA(0, 1);
  if (NT > 1) {
    stageA(1, 0); stageB(1, 1); stageA(1, 1);
    vwait_steady();
  } else {
    asm volatile("s_waitcnt vmcnt(0)" ::: "memory");
  }
  BARRIER();

  for (int t = 0; t < NT; ++t) {
    const int b = t & 1;
    // phase 0: (qa0,qb0); stage B_q0(t+1)
    readA(b, 0); readB(b, 0);
    if (t + 1 < NT) stageB(t + 1, 0);
    BARRIER(); LGKM0();
    __builtin_amdgcn_s_setprio(1); mf(0, 0); __builtin_amdgcn_s_setprio(0);
    BARRIER();
    // phase 1: (qa0,qb1); stage A_q0(t+2)
    readB(b, 1);
    if (t + 2 < NT) stageA(t + 2, 0);
    BARRIER(); LGKM0();
    __builtin_amdgcn_s_setprio(1); mf(0, 1); __builtin_amdgcn_s_setprio(0);
    BARRIER();
    // phase 2: (qa1,qb1); stage B_q1(t+2)
    readA(b, 1);
    if (t + 2 < NT) stageB(t + 2, 1);
    BARRIER(); LGKM0();
    __builtin_amdgcn_s_setprio(1); mf(1, 1); __builtin_amdgcn_s_setprio(0);
    BARRIER();
    // phase 3: (qa1,qb0); stage A_q1(t+2); boundary vmcnt (counted, never 0
    // in steady state -- drains exactly through tile t+1, leaves tile t+2's
    // three prefetched regions in flight)
    readB(b, 0);
    if (t + 2 < NT) stageA(t + 2, 1);
    BARRIER(); LGKM0();
    __builtin_amdgcn_s_setprio(1); mf(1, 0); __builtin_amdgcn_s_setprio(0);
    if (t + 2 < NT) vwait_steady();
    else            asm volatile("s_waitcnt vmcnt(0)" ::: "memory");
    BARRIER();
  }

  const int rb = ((lane >> 4) & 3) * 4;
#pragma unroll
  for (int qa = 0; qa < 2; ++qa)
#pragma unroll
    for (int i = 0; i < 4; ++i)
#pragma unroll
      for (int qb = 0; qb < 2; ++qb)
#pragma unroll
        for (int j = 0; j < JT; ++j)
#pragma unroll
          for (int r = 0; r < 4; ++r)
            epi(wm * 128 + qa * 64 + i * 16 + rb + r,
                wn * CW + qb * QBS + j * 16 + ln,
                acc[qa * 4 + i][qb * JT + j][r]);
}

// y(bf16) = attn @ W_o^T + x    grid: 64m x 8n = 512 blocks
__global__ __launch_bounds__(512) void k_gemm_wo(const unsigned short* __restrict__ A,
                                                 const unsigned short* __restrict__ Bt,
                                                 const float* __restrict__ x,
                                                 unsigned short* __restrict__ y) {
  const int bid = blockIdx.x;
  const int swz = (bid & 7) * 64 + (bid >> 3);
  const int m0 = (swz >> 3) * 256, n0 = (swz & 7) * 256;
  gemm8p<256>(A + (size_t)m0 * 2048, Bt + (size_t)n0 * 2048, 2048, 2048, 2048,
              [=](int r, int cc, float v) {
                size_t idx = (size_t)(m0 + r) * 2048 + n0 + cc;
                y[idx] = f2b(v + x[idx]);
              });
}

// act = silu(h @ upW)   grid: 16m x 32n = 512 blocks
__global__ __launch_bounds__(512) void k_gemm_up2(const unsigned short* __restrict__ A,
                                                  const unsigned short* __restrict__ Bt,
                                                  unsigned short* __restrict__ act) {
  const int bid = blockIdx.x;
  const int swz = (bid & 7) * 64 + (bid >> 3);
  const int m0 = (swz >> 5) * 256, n0 = (swz & 31) * 256;
  gemm8p<256>(A + (size_t)m0 * 2048, Bt + (size_t)n0 * 2048, 2048, 2048, 2048,
              [=](int r, int cc, float v) {
                float s = v / (1.f + __expf(-v));
                act[(size_t)(m0 + r) * 8192 + n0 + cc] = f2b(s);
              });
}

// act *= (h @ gateW)   (RMW epilogue; act holds silu(up))
__global__ __launch_bounds__(512) void k_gemm_gatem(const unsigned short* __restrict__ A,
                                                    const unsigned short* __restrict__ Bt,
                                                    unsigned short* act) {
  const int bid = blockIdx.x;
  const int swz = (bid & 7) * 64 + (bid >> 3);
  const int m0 = (swz >> 5) * 256, n0 = (swz & 31) * 256;
  gemm8p<256>(A + (size_t)m0 * 2048, Bt + (size_t)n0 * 2048, 2048, 2048, 2048,
              [=](int r, int cc, float v) {
                size_t idx = (size_t)(m0 + r) * 8192 + n0 + cc;
                act[idx] = f2b(v * b2f(act[idx]));
              });
}

// outc(f32) = act @ downW^T + h   grid: 16m x 16n = 256 blocks (BN=128)
__global__ __launch_bounds__(512) void k_gemm_down2(const unsigned short* __restrict__ A,
                                                    const unsigned short* __restrict__ Bt,
                                                    const unsigned short* __restrict__ hbuf,
                                                    float* __restrict__ outc) {
  const int bid = blockIdx.x;
  const int swz = (bid & 7) * 32 + (bid >> 3);
  const int m0 = (swz >> 4) * 256, n0 = (swz & 15) * 128;
  gemm8p<128>(A + (size_t)m0 * 8192, Bt + (size_t)n0 * 8192, 8192, 8192, 8192,
              [=](int r, int cc, float v) {
                size_t idx = (size_t)(m0 + r) * 2048 + n0 + cc;
                outc[idx] = v + b2f(hbuf[idx]);
              });
}

// transpose+convert f32 [R][C] -> bf16 [C][R]
__global__ __launch_bounds__(256) void k_tc(const float* __restrict__ in,
                                            unsigned short* __restrict__ out, int R, int C) {
  __shared__ float tile[64][65];
  const int c0 = blockIdx.x * 64, r0 = blockIdx.y * 64;
  const int tid = threadIdx.x;
#pragma unroll
  for (int p = 0; p < 16; ++p) {
    int l = p * 256 + tid;
    int ir = l >> 6, ic = l & 63;
    tile[ic][ir] = in[(size_t)(r0 + ir) * C + c0 + ic];
  }
  __syncthreads();
#pragma unroll
  for (int p = 0; p < 16; ++p) {
    int l = p * 256 + tid;
    int oc = l >> 6, orr = l & 63;
    out[(size_t)(c0 + oc) * R + r0 + orr] = f2b(tile[oc][orr]);
  }
}

__global__ __launch_bounds__(256) void k_zero(float* __restrict__ p, int n) {
  int i = blockIdx.x * 256 + threadIdx.x;
  if (i < n) p[i] = 0.f;
}

// Wq_proj[h] = W_uq[:, h*128:+128] @ omega (f32); same for K-side.
__global__ __launch_bounds__(256) void k_wproj(const float* __restrict__ W_uq,
                                               const float* __restrict__ W_uk,
                                               const float* __restrict__ omega,
                                               float* __restrict__ wqp, float* __restrict__ wkp) {
  const int bi = blockIdx.x;
  const float* W;
  float* outp;
  int ldw, col0;
  if (bi < 16) { W = W_uq; outp = wqp + bi * 4096; ldw = 2048; col0 = bi * 128; }
  else         { W = W_uk; outp = wkp + (bi - 16) * 4096; ldw = 1024; col0 = (bi - 16) * 128; }
  __shared__ float om[128][64];
  const int tid = threadIdx.x;
#pragma unroll
  for (int p = 0; p < 32; ++p) {
    int l = p * 256 + tid;
    om[l >> 6][l & 63] = omega[l];
  }
  __syncthreads();
  const int r = tid >> 2, f0 = (tid & 3) * 16;
  float acc[16];
#pragma unroll
  for (int f = 0; f < 16; ++f) acc[f] = 0.f;
  const float* wrow = W + (size_t)r * ldw + col0;
  for (int d = 0; d < 128; ++d) {
    float w = wrow[d];
#pragma unroll
    for (int f = 0; f < 16; ++f) acc[f] += w * om[d][f0 + f];
  }
#pragma unroll
  for (int f = 0; f < 16; ++f) outp[r * 64 + f0 + f] = acc[f];
}

// c = x @ [W_dq | W_dkv], pure f32. Block: 64 tokens x 128 cols.
__global__ __launch_bounds__(256) void k_cgemm(const float* __restrict__ x,
                                               const float* __restrict__ W_dq,
                                               const float* __restrict__ W_dkv,
                                               float* __restrict__ cbuf) {
  __shared__ float xs[64][65];
  __shared__ float wsh[64][128];
  const int tok0 = blockIdx.x * 64;
  const int tid = threadIdx.x;
  const int ty = tid >> 3, tx = tid & 7;
  const int t0 = ty * 2, c0 = tx * 16;
  float acc[2][16];
#pragma unroll
  for (int i = 0; i < 2; ++i)
#pragma unroll
    for (int e = 0; e < 16; ++e) acc[i][e] = 0.f;
  for (int kb = 0; kb < 2048; kb += 64) {
#pragma unroll
    for (int p = 0; p < 16; ++p) {
      int l = p * 256 + tid;
      int tr = l >> 6, kd = l & 63;
      xs[tr][kd] = x[(size_t)(tok0 + tr) * 2048 + kb + kd];
    }
#pragma unroll
    for (int p = 0; p < 32; ++p) {
      int l = p * 256 + tid;
      int kd = l >> 7, c = l & 127;
      wsh[kd][c] = (c < 64) ? W_dq[(size_t)(kb + kd) * 64 + c]
                            : W_dkv[(size_t)(kb + kd) * 64 + (c - 64)];
    }
    __syncthreads();
    for (int kd = 0; kd < 64; ++kd) {
      float a0 = xs[t0][kd], a1 = xs[t0 + 1][kd];
#pragma unroll
      for (int e = 0; e < 16; ++e) {
        float w = wsh[kd][c0 + e];
        acc[0][e] += a0 * w;
        acc[1][e] += a1 * w;
      }
    }
    __syncthreads();
  }
#pragma unroll
  for (int i = 0; i < 2; ++i)
#pragma unroll
    for (int e = 0; e < 16; ++e)
      cbuf[(size_t)(tok0 + t0 + i) * 128 + c0 + e] = acc[i][e];
}

// phi_k (f32, transposed [bh][f=128][s=4096]) + z accumulation (atomicAdd).
__global__ __launch_bounds__(256) void k_phikz(const float* __restrict__ c,
                                               const float* __restrict__ wkp,
                                               float* __restrict__ phikT,
                                               float* __restrict__ z) {
  const int s0 = blockIdx.x * 64;
  const int bh = blockIdx.y;  // b*8+hkv
  const int b = bh >> 3, hkv = bh & 7;
  __shared__ float ck[64][65];
  __shared__ float wp[64][68];
  const int tid = threadIdx.x;
#pragma unroll
  for (int p = 0; p < 16; ++p) {
    int l = p * 256 + tid;
    int sr = l >> 6, d = l & 63;
    ck[sr][d] = c[(size_t)(b * 4096 + s0 + sr) * 128 + 64 + d];
    wp[sr][d] = wkp[hkv * 4096 + l];
  }
  __syncthreads();
  const int ty = tid & 31, fx = tid >> 5;
  const int f0 = fx * 8, r0 = ty * 2;
  float pr[2][8];
#pragma unroll
  for (int rr = 0; rr < 2; ++rr)
#pragma unroll
    for (int ff = 0; ff < 8; ++ff) pr[rr][ff] = 0.f;
  for (int d = 0; d < 64; ++d) {
    f32x4 w0 = *(const f32x4*)&wp[d][f0];
    f32x4 w1 = *(const f32x4*)&wp[d][f0 + 4];
    float c0v = ck[r0][d], c1v = ck[r0 + 1][d];
#pragma unroll
    for (int e = 0; e < 4; ++e) {
      pr[0][e] += c0v * w0[e]; pr[0][4 + e] += c0v * w1[e];
      pr[1][e] += c1v * w0[e]; pr[1][4 + e] += c1v * w1[e];
    }
  }
  float* obase = phikT + (size_t)bh * 524288 + s0 + r0;
  float zc[8], zs2[8];
#pragma unroll
  for (int ff = 0; ff < 8; ++ff) {
    float sv0, cv0, sv1, cv1;
    __sincosf(pr[0][ff], &sv0, &cv0);
    __sincosf(pr[1][ff], &sv1, &cv1);
    float c0 = cv0 * 0.125f, c1 = cv1 * 0.125f;
    float s0v = sv0 * 0.125f, s1v = sv1 * 0.125f;
    f32x2 co; co[0] = c0; co[1] = c1;
    f32x2 si; si[0] = s0v; si[1] = s1v;
    *(f32x2*)(obase + (size_t)(f0 + ff) * 4096) = co;
    *(f32x2*)(obase + (size_t)(64 + f0 + ff) * 4096) = si;
    zc[ff] = c0 + c1;
    zs2[ff] = s0v + s1v;
  }
#pragma unroll
  for (int off = 16; off; off >>= 1) {
#pragma unroll
    for (int ff = 0; ff < 8; ++ff) {
      zc[ff] += __shfl_down(zc[ff], off);
      zs2[ff] += __shfl_down(zs2[ff], off);
    }
  }
  if (ty == 0) {
#pragma unroll
    for (int ff = 0; ff < 8; ++ff) {
      atomicAdd(&z[bh * 128 + f0 + ff], zc[ff]);
      atomicAdd(&z[bh * 128 + 64 + f0 + ff], zs2[ff]);
    }
  }
}

// v = c_kv @ W_uv (f32), transposed [bh][d=128][s=4096].
__global__ __launch_bounds__(256) void k_vf(const float* __restrict__ c,
                                            const float* __restrict__ W_uv,
                                            float* __restrict__ vT) {
  const int s0 = blockIdx.x * 64;
  const int bh = blockIdx.y;
  const int b = bh >> 3, hkv = bh & 7;
  __shared__ float ck[64][65];
  __shared__ float wv[64][132];
  const int tid = threadIdx.x;
#pragma unroll
  for (int p = 0; p < 16; ++p) {
    int l = p * 256 + tid;
    int sr = l >> 6, d = l & 63;
    ck[sr][d] = c[(size_t)(b * 4096 + s0 + sr) * 128 + 64 + d];
  }
#pragma unroll
  for (int p = 0; p < 32; ++p) {
    int l = p * 256 + tid;
    int rr = l >> 7, d = l & 127;
    wv[rr][d] = W_uv[(size_t)rr * 1024 + hkv * 128 + d];
  }
  __syncthreads();
  const int ty = tid & 15, tx = tid >> 4;
  const int r0 = ty * 4, d0 = tx * 8;
  float acc[4][8];
#pragma unroll
  for (int rr = 0; rr < 4; ++rr)
#pragma unroll
    for (int dd = 0; dd < 8; ++dd) acc[rr][dd] = 0.f;
  for (int kk = 0; kk < 64; ++kk) {
    f32x4 w0 = *(const f32x4*)&wv[kk][d0];
    f32x4 w1 = *(const f32x4*)&wv[kk][d0 + 4];
    float cv[4];
#pragma unroll
    for (int rr = 0; rr < 4; ++rr) cv[rr] = ck[r0 + rr][kk];
#pragma unroll
    for (int rr = 0; rr < 4; ++rr)
#pragma unroll
      for (int e = 0; e < 4; ++e) {
        acc[rr][e] += cv[rr] * w0[e];
        acc[rr][4 + e] += cv[rr] * w1[e];
      }
  }
  float* obase = vT + (size_t)bh * 524288 + s0 + r0;
#pragma unroll
  for (int dd = 0; dd < 8; ++dd) {
    f32x4 pv;
    pv[0] = acc[0][dd]; pv[1] = acc[1][dd]; pv[2] = acc[2][dd]; pv[3] = acc[3][dd];
    *(f32x4*)(obase + (size_t)(d0 + dd) * 4096) = pv;
  }
}

// kv[f][d] = sum_s phi_k[s,f]*v[s,d], f32. grid (16 = fq*4+dq, 32 bh).
__global__ __launch_bounds__(256) void k_kvf2(const float* __restrict__ phikT,
                                              const float* __restrict__ vT,
                                              float* __restrict__ kvf) {
  const int fq = blockIdx.x >> 2, dq = blockIdx.x & 3, bh = blockIdx.y;
  const float* pT = phikT + (size_t)bh * 524288 + (size_t)fq * 32 * 4096;
  const float* vB = vT + (size_t)bh * 524288 + (size_t)dq * 32 * 4096;
  __shared__ float ps[64][33];
  __shared__ float vs[64][33];
  const int tid = threadIdx.x;
  const int fi = tid >> 3, d0 = (tid & 7) * 4;
  f32x4 acc = {0.f, 0.f, 0.f, 0.f};
  for (int ss = 0; ss < 4096; ss += 64) {
#pragma unroll
    for (int p = 0; p < 8; ++p) {
      int l = p * 256 + tid;
      int rr = l >> 6, si = l & 63;
      ps[si][rr] = pT[(size_t)rr * 4096 + ss + si];
      vs[si][rr] = vB[(size_t)rr * 4096 + ss + si];
    }
    __syncthreads();
    for (int si = 0; si < 64; ++si) {
      float pv = ps[si][fi];
#pragma unroll
      for (int j = 0; j < 4; ++j) acc[j] += pv * vs[si][d0 + j];
    }
    __syncthreads();
  }
  float* o = kvf + ((size_t)bh * 128 + fq * 32 + fi) * 128 + dq * 32 + d0;
  *(f32x4*)o = acc;
}

// Fused attention: phi_q + den (register-reduced) + num over all 128 d.
// grid (64 s-tiles, 64 bh).
__global__ __launch_bounds__(256) void k_attn2(const float* __restrict__ c,
                                               const float* __restrict__ wqp,
                                               const float* __restrict__ zb,
                                               const float* __restrict__ kvf,
                                               unsigned short* __restrict__ attn) {
  const int s0 = blockIdx.x * 64;
  const int bh = blockIdx.y;            // b*16 + head
  const int b = bh >> 4, hh = bh & 15;
  const int bhk = (b << 3) + (hh >> 1);
  __shared__ float wq[4096];
  __shared__ float cqt[64][33];
  __shared__ float phl[32][130];
  __shared__ float kvl[128][32];
  __shared__ float zl[128];
  __shared__ float denl[32];
  const int tid = threadIdx.x;
  if (tid < 128) zl[tid] = zb[bhk * 128 + tid];
#pragma unroll
  for (int p = 0; p < 16; ++p) wq[p * 256 + tid] = wqp[hh * 4096 + p * 256 + tid];
  const int fx = tid & 7, ty = tid >> 3;   // f0 = fx*8, token-row = ty (0..31)
  const int f0 = fx * 8;
  for (int hf = 0; hf < 2; ++hf) {
    __syncthreads();
#pragma unroll
    for (int p = 0; p < 8; ++p) {
      int l = p * 256 + tid;
      int sr = l >> 6, dd = l & 63;
      cqt[dd][sr] = c[(size_t)(b * 4096 + s0 + hf * 32 + sr) * 128 + dd];
    }
    __syncthreads();
    // proj for token ty, features f0..f0+7
    float pr[8];
#pragma unroll
    for (int ff = 0; ff < 8; ++ff) pr[ff] = 0.f;
    for (int dd = 0; dd < 64; ++dd) {
      f32x4 w0 = *(const f32x4*)(wq + dd * 64 + f0);
      f32x4 w1 = *(const f32x4*)(wq + dd * 64 + f0 + 4);
      float cv = cqt[dd][ty];
#pragma unroll
      for (int e = 0; e < 4; ++e) { pr[e] += cv * w0[e]; pr[4 + e] += cv * w1[e]; }
    }
    float dpart = 0.f;
#pragma unroll
    for (int ff = 0; ff < 8; ++ff) {
      float sv, cv;
      __sincosf(pr[ff], &sv, &cv);
      cv *= 0.125f; sv *= 0.125f;
      phl[ty][f0 + ff] = cv;
      phl[ty][64 + f0 + ff] = sv;
      dpart += cv * zl[f0 + ff] + sv * zl[64 + f0 + ff];
    }
    dpart += __shfl_down(dpart, 4);
    dpart += __shfl_down(dpart, 2);
    dpart += __shfl_down(dpart, 1);
    if (fx == 0) denl[ty] = dpart + 1e-6f;
    __syncthreads();
    for (int dq = 0; dq < 4; ++dq) {
#pragma unroll
      for (int p = 0; p < 16; ++p) {
        int l = p * 256 + tid;
        int f = l >> 5, j = l & 31;
        kvl[f][j] = kvf[(size_t)bhk * 16384 + (size_t)f * 128 + dq * 32 + j];
      }
      __syncthreads();
      const int row = tid >> 3, d0 = (tid & 7) * 4;
      f32x4 acc = {0.f, 0.f, 0.f, 0.f};
      for (int f = 0; f < 128; f += 2) {
        f32x2 pa = *(const f32x2*)&phl[row][f];
        f32x4 k0 = *(const f32x4*)&kvl[f][d0];
        f32x4 k1 = *(const f32x4*)&kvl[f + 1][d0];
#pragma unroll
        for (int j = 0; j < 4; ++j) acc[j] += pa[0] * k0[j] + pa[1] * k1[j];
      }
      const float dn = denl[row];
      u16x4 o4;
#pragma unroll
      for (int j = 0; j < 4; ++j) o4[j] = f2b(acc[j] / dn);
      *(u16x4*)(attn + (size_t)(b * 4096 + s0 + hf * 32 + row) * 2048 + hh * 128 + dq * 32 + d0) = o4;
      __syncthreads();
    }
  }
}

// LayerNorm bf16->bf16 (ln1)
__global__ __launch_bounds__(256) void k_ln_b2b(const unsigned short* __restrict__ in,
                                                const float* __restrict__ g,
                                                const float* __restrict__ bb,
                                                unsigned short* __restrict__ ob) {
  const int row = blockIdx.x;
  const unsigned short* xr = in + (size_t)row * 2048;
  float vals[8], s = 0.f, ss = 0.f;
#pragma unroll
  for (int i = 0; i < 8; ++i) {
    float v = b2f(xr[i * 256 + threadIdx.x]);
    vals[i] = v; s += v; ss += v * v;
  }
#pragma unroll
  for (int off = 32; off; off >>= 1) { s += __shfl_down(s, off); ss += __shfl_down(ss, off); }
  __shared__ float red[8];
  const int wave = threadIdx.x >> 6;
  if ((threadIdx.x & 63) == 0) { red[wave * 2] = s; red[wave * 2 + 1] = ss; }
  __syncthreads();
  float S = red[0] + red[2] + red[4] + red[6];
  float SS = red[1] + red[3] + red[5] + red[7];
  float mu = S * (1.f / 2048.f);
  float var = SS * (1.f / 2048.f) - mu * mu;
  float inv = rsqrtf(var + 1e-5f);
#pragma unroll
  for (int i = 0; i < 8; ++i) {
    int col = i * 256 + threadIdx.x;
    ob[(size_t)row * 2048 + col] = f2b((vals[i] - mu) * inv * g[col] + bb[col]);
  }
}

// In-place LayerNorm f32 (ln2 on out rows)
__global__ __launch_bounds__(256) void k_ln_ip(float* __restrict__ io,
                                               const float* __restrict__ g,
                                               const float* __restrict__ bb) {
  const int row = blockIdx.x;
  float* xr = io + (size_t)row * 2048;
  float vals[8], s = 0.f, ss = 0.f;
#pragma unroll
  for (int i = 0; i < 8; ++i) {
    float v = xr[i * 256 + threadIdx.x];
    vals[i] = v; s += v; ss += v * v;
  }
#pragma unroll
  for (int off = 32; off; off >>= 1) { s += __shfl_down(s, off); ss += __shfl_down(ss, off); }
  __shared__ float red[8];
  const int wave = threadIdx.x >> 6;
  if ((threadIdx.x & 63) == 0) { red[wave * 2] = s; red[wave * 2 + 1] = ss; }
  __syncthreads();
  float S = red[0] + red[2] + red[4] + red[6];
  float SS = red[1] + red[3] + red[5] + red[7];
  float mu = S * (1.f / 2048.f);
  float var = SS * (1.f / 2048.f) - mu * mu;
  float inv = rsqrtf(var + 1e-5f);
#pragma unroll
  for (int i = 0; i < 8; ++i) {
    int col = i * 256 + threadIdx.x;
    xr[col] = (vals[i] - mu) * inv * g[col] + bb[col];
  }
}

// ---------------------------------------------------------------------------
extern "C" void kernel_launch(void* const* d_in, const int* in_sizes, int n_in,
                              void* d_out, int out_size, void* d_ws, size_t ws_size,
                              hipStream_t stream) {
  (void)in_sizes; (void)n_in; (void)out_size; (void)ws_size;
  const float* x     = (const float*)d_in[0];
  const float* W_dq  = (const float*)d_in[1];
  const float* W_uq  = (const float*)d_in[2];
  const float* W_dkv = (const float*)d_in[3];
  const float* W_uk  = (const float*)d_in[4];
  const float* W_uv  = (const float*)d_in[5];
  const float* omega = (const float*)d_in[6];
  const float* W_o   = (const float*)d_in[7];
  const float* ln1g  = (const float*)d_in[8];
  const float* ln1b  = (const float*)d_in[9];
  const float* gateW = (const float*)d_in[10];
  const float* upW   = (const float*)d_in[11];
  const float* downW = (const float*)d_in[12];
  const float* ln2g  = (const float*)d_in[13];
  const float* ln2b  = (const float*)d_in[14];
  float* out = (float*)d_out;

  // Workspace (232 MiB, liveness-overlaid):
  // R0 [0,64M):    phikTf(f32) -> gatet|upt
  // R1 [64,128M):  vTf(f32) -> attn(bf16) -> hb(bf16)
  // R2 [128,192M): cbuf/wqp/wkp/zb/kvf -> y(bf16) -> act(64MB)
  // R3 [192,200M): wot   R4 [200,232M): downt
  char* w = (char*)d_ws;
  float*          phikTf = (float*)(w);
  float*          vTf    = (float*)(w + 67108864);
  unsigned short* attn   = (unsigned short*)(w + 67108864);
  unsigned short* hb     = (unsigned short*)(w + 67108864);
  unsigned short* gatet  = (unsigned short*)(w);
  unsigned short* upt    = (unsigned short*)(w + 33554432);
  char* C = w + 134217728;
  float*          cbuf = (float*)(C);
  float*          wqp  = (float*)(C + 8388608);
  float*          wkp  = (float*)(C + 8650752);
  float*          zb   = (float*)(C + 8781824);
  float*          kvf  = (float*)(C + 8798208);
  unsigned short* y    = (unsigned short*)(C);
  unsigned short* act  = (unsigned short*)(C);
  unsigned short* wot   = (unsigned short*)(w + 201326592);
  unsigned short* downt = (unsigned short*)(w + 209715200);

  // phase 0: prep
  k_zero<<<16, 256, 0, stream>>>(zb, 4096);
  k_wproj<<<24, 256, 0, stream>>>(W_uq, W_uk, omega, wqp, wkp);
  k_tc<<<dim3(32, 32), 256, 0, stream>>>(W_o, wot, 2048, 2048);

  // phase 1: latents (f32)
  k_cgemm<<<256, 256, 0, stream>>>(x, W_dq, W_dkv, cbuf);

  // phase 2: phi_k + z, v (f32)
  k_phikz<<<dim3(64, 32), 256, 0, stream>>>(cbuf, wkp, phikTf, zb);
  k_vf<<<dim3(64, 32), 256, 0, stream>>>(cbuf, W_uv, vTf);

  // phase 3: kv (f32), fused phi_q/den/num -> attn(bf16)
  k_kvf2<<<dim3(16, 32), 256, 0, stream>>>(phikTf, vTf, kvf);
  k_attn2<<<dim3(64, 64), 256, 0, stream>>>(cbuf, wqp, zb, kvf, attn);

  // phase 4: W_o + residual + LN1 (8-phase 256^2 GEMM, 512 blocks)
  k_gemm_wo<<<dim3(512), 512, 0, stream>>>(attn, wot, x, y);
  k_ln_b2b<<<16384, 256, 0, stream>>>(y, ln1g, ln1b, hb);

  // phase 5: FFN weight transposes into freed regions
  k_tc<<<dim3(128, 32), 256, 0, stream>>>(gateW, gatet, 2048, 8192);
  k_tc<<<dim3(128, 32), 256, 0, stream>>>(upW, upt, 2048, 8192);
  k_tc<<<dim3(32, 128), 256, 0, stream>>>(downW, downt, 8192, 2048);

  // phase 6: FFN in 4 chunks of 4096 rows; no gate buffer, LN2 in-place on out
  for (int cix = 0; cix < 4; ++cix) {
    const unsigned short* hbc = hb + (size_t)cix * 4096 * 2048;
    float* outc = out + (size_t)cix * 4096 * 2048;
    k_gemm_up2<<<dim3(512), 512, 0, stream>>>(hbc, upt, act);
    k_gemm_gatem<<<dim3(512), 512, 0, stream>>>(hbc, gatet, act);
    k_gemm_down2<<<dim3(256), 512, 0, stream>>>(act, downt, hbc, outc);
    k_ln_ip<<<4096, 256, 0, stream>>>(outc, ln2g, ln2b);
  }
}

// Round 3
// 2846.991 us; speedup vs baseline: 1.3228x; 1.1099x over previous
//
#include <hip/hip_runtime.h>
#include <stdint.h>
#include <math.h>

// ---------------------------------------------------------------------------
// MLGKA layer forward, MI355X (gfx950).
// R7: attention path MFMA-ized.
//  - k_attn2 (327us, MfmaUtil=0, 22% occ) split into k_phiq (f32 proj/sincos/
//    den, 25KB LDS -> ~3x occupancy, writes phi_q bf16 + 1/den) and k_num
//    (batched bf16 MFMA GEMM [4096x128]@[128x128] per head, m97 gemm_core).
//  - k_kvf2 (f32 VALU, ~512MB streamed) replaced by k_kvg (m97 gemm_core,
//    bf16, K=4096 split 8-way into f32 partials, 256 blocks = 1/CU) +
//    k_kvredt (reduce partials + transpose -> kv bf16 [d][f]).
//  - k_phikz / k_vf now write bf16 phi_k / v (half the write traffic).
//  - proj & den stay f32 (Cauchy-tailed omega => phase-sensitive).
// FFN/W_o GEMMs: unchanged verified 256^2 8-phase schedule (gemm8p).
// Workspace: 232 MiB, liveness-overlaid (phiq overwrites phikT after k_kvg;
// attn overwrites vT after k_kvg).
// ---------------------------------------------------------------------------

typedef __bf16 bf16x8 __attribute__((ext_vector_type(8)));
typedef float f32x4 __attribute__((ext_vector_type(4)));
typedef float f32x2 __attribute__((ext_vector_type(2)));
typedef unsigned short u16x8 __attribute__((ext_vector_type(8)));
typedef unsigned short u16x4 __attribute__((ext_vector_type(4)));
typedef unsigned short u16x2 __attribute__((ext_vector_type(2)));

#define DEV __device__ __forceinline__

DEV unsigned short f2b(float f) {
  union { float f; unsigned int u; } v;
  v.f = f;
  unsigned int u = v.u;
  return (unsigned short)((u + 0x7FFFu + ((u >> 16) & 1u)) >> 16);  // RNE
}
DEV float b2f(unsigned short h) {
  union { unsigned int u; float f; } v;
  v.u = ((unsigned int)h) << 16;
  return v.f;
}

DEV void async16(const void* g, void* l) {
  typedef __attribute__((address_space(1))) unsigned int* gp_t;
  typedef __attribute__((address_space(3))) unsigned int* lp_t;
  __builtin_amdgcn_global_load_lds((gp_t)(g), (lp_t)(l), 16, 0, 0);
}

#define SCHED0() __builtin_amdgcn_sched_barrier(0)
#define BARRIER() do { SCHED0(); __builtin_amdgcn_s_barrier(); SCHED0(); } while (0)
#define LGKM0() do { asm volatile("s_waitcnt lgkmcnt(0)" ::: "memory"); SCHED0(); } while (0)

// ---------------------------------------------------------------------------
// m97-style 2-barrier MFMA core: C[128x128] = A[128xK] * Bt[128xK]^T.
// Used for the small batched attention GEMMs (K=128 / K-chunked kv).
// ---------------------------------------------------------------------------
template <typename Epi>
DEV void gemm_core(const unsigned short* __restrict__ A,
                   const unsigned short* __restrict__ Bt,
                   int K, int lda, int ldb, Epi epi) {
  __shared__ alignas(16) unsigned short As[128 * 64];
  __shared__ alignas(16) unsigned short Bs[128 * 64];
  const int tid = threadIdx.x;
  const int lane = tid & 63;
  const int wr = ((tid >> 6) >> 1) * 64;
  const int wc = ((tid >> 6) & 1) * 64;
  const int ln = lane & 15;
  const int kq = (lane >> 4) * 8;

  const f32x4 fz = {0.f, 0.f, 0.f, 0.f};
  f32x4 acc[4][4];
#pragma unroll
  for (int i = 0; i < 4; ++i)
#pragma unroll
    for (int j = 0; j < 4; ++j) acc[i][j] = fz;

  for (int kb = 0; kb < K; kb += 64) {
#pragma unroll
    for (int c = 0; c < 4; ++c) {
      int o = (c * 256 + tid) * 16;
      int row = o >> 7;
      int ke = (o & 127) >> 1;
      async16(A + (size_t)row * lda + kb + ke, (void*)(As + (o >> 1)));
      async16(Bt + (size_t)row * ldb + kb + ke, (void*)(Bs + (o >> 1)));
    }
    __syncthreads();
#pragma unroll
    for (int t = 0; t < 2; ++t) {
      const int kk = t * 32 + kq;
      bf16x8 av[4], bv[4];
#pragma unroll
      for (int i = 0; i < 4; ++i)
        av[i] = *(const bf16x8*)(As + (wr + i * 16 + ln) * 64 + kk);
#pragma unroll
      for (int j = 0; j < 4; ++j)
        bv[j] = *(const bf16x8*)(Bs + (wc + j * 16 + ln) * 64 + kk);
#pragma unroll
      for (int i = 0; i < 4; ++i)
#pragma unroll
        for (int j = 0; j < 4; ++j)
          acc[i][j] = __builtin_amdgcn_mfma_f32_16x16x32_bf16(av[i], bv[j], acc[i][j], 0, 0, 0);
    }
    __syncthreads();
  }
  const int rb = (lane >> 4) * 4;
#pragma unroll
  for (int i = 0; i < 4; ++i)
#pragma unroll
    for (int j = 0; j < 4; ++j)
#pragma unroll
      for (int r = 0; r < 4; ++r)
        epi(wr + i * 16 + rb + r, wc + j * 16 + ln, acc[i][j][r]);
}

// ---------------------------------------------------------------------------
// 8-phase GEMM core (verified R6): C[256 x BN] = A[256 x K] * Bt[BN x K]^T.
// ---------------------------------------------------------------------------
template <int BN, typename Epi>
DEV void gemm8p(const unsigned short* __restrict__ A,
                const unsigned short* __restrict__ Bt,
                int K, int lda, int ldb, Epi epi) {
  constexpr int CW = BN / 4;
  constexpr int JT = CW / 32;
  constexpr int QBS = CW / 2;
  constexpr int SZB = BN * 64;
  constexpr int BUFB = 2 * 16384 + 2 * SZB;
  constexpr int LB = BN / 128;
  constexpr int VMC = 4 + LB;
  __shared__ alignas(16) char lds[2 * BUFB];

  const int tid = threadIdx.x;
  const int lane = tid & 63;
  const int wave = tid >> 6;
  const int wm = wave >> 2, wn = wave & 3;
  const int ln = lane & 15;
  const int kq2 = ((lane >> 4) & 3) << 4;

  int srA[2], kbA[2], srB[2], kbB[2];
#pragma unroll
  for (int p = 0; p < 2; ++p) {
    int o = (p * 512 + tid) * 16;
    int x = o ^ (((o >> 9) & 1) << 5);
    srA[p] = x >> 7; kbA[p] = (x & 127) >> 1;
  }
#pragma unroll
  for (int p = 0; p < LB; ++p) {
    int o = (p * 512 + tid) * 16;
    int x = o ^ (((o >> 9) & 1) << 5);
    srB[p] = x >> 7; kbB[p] = (x & 127) >> 1;
  }

  const int NT = K >> 6;

  auto stageA = [&](int T, int qa) {
    char* dst = lds + (T & 1) * BUFB + qa * 16384;
    const unsigned short* src = A + T * 64;
#pragma unroll
    for (int p = 0; p < 2; ++p) {
      int r = ((srA[p] >> 6) << 7) | (qa << 6) | (srA[p] & 63);
      async16(src + (size_t)r * lda + kbA[p], dst + (p * 512 + tid) * 16);
    }
  };
  auto stageB = [&](int T, int qb) {
    char* dst = lds + (T & 1) * BUFB + 32768 + qb * SZB;
    const unsigned short* src = Bt + T * 64;
#pragma unroll
    for (int p = 0; p < LB; ++p) {
      int n = (srB[p] / QBS) * CW + qb * QBS + (srB[p] % QBS);
      async16(src + (size_t)n * ldb + kbB[p], dst + (p * 512 + tid) * 16);
    }
  };

  bf16x8 av[4][2], bv[JT][2];
  auto readA = [&](int b, int qa) {
#pragma unroll
    for (int i = 0; i < 4; ++i) {
      int sr = wm * 64 + i * 16 + ln;
      const char* rp = lds + b * BUFB + qa * 16384 + sr * 128;
      int sw = (sr & 4) << 3;
      av[i][0] = *(const bf16x8*)(rp + (kq2 ^ sw));
      av[i][1] = *(const bf16x8*)(rp + ((64 + kq2) ^ sw));
    }
  };
  auto readB = [&](int b, int qb) {
#pragma unroll
    for (int j = 0; j < JT; ++j) {
      int sr = wn * QBS + j * 16 + ln;
      const char* rp = lds + b * BUFB + 32768 + qb * SZB + sr * 128;
      int sw = (sr & 4) << 3;
      bv[j][0] = *(const bf16x8*)(rp + (kq2 ^ sw));
      bv[j][1] = *(const bf16x8*)(rp + ((64 + kq2) ^ sw));
    }
  };

  f32x4 acc[8][2 * JT];
  const f32x4 fz = {0.f, 0.f, 0.f, 0.f};
#pragma unroll
  for (int i = 0; i < 8; ++i)
#pragma unroll
    for (int j = 0; j < 2 * JT; ++j) acc[i][j] = fz;

  auto mf = [&](int qa, int qb) {
#pragma unroll
    for (int tt = 0; tt < 2; ++tt)
#pragma unroll
      for (int i = 0; i < 4; ++i)
#pragma unroll
        for (int j = 0; j < JT; ++j)
          acc[qa * 4 + i][qb * JT + j] = __builtin_amdgcn_mfma_f32_16x16x32_bf16(
              av[i][tt], bv[j][tt], acc[qa * 4 + i][qb * JT + j], 0, 0, 0);
  };

  auto vwait_steady = [&]() {
    if constexpr (VMC == 6) asm volatile("s_waitcnt vmcnt(6)" ::: "memory");
    else                    asm volatile("s_waitcnt vmcnt(5)" ::: "memory");
  };

  stageA(0, 0); stageB(0, 0); stageB(0, 1); stageA(0, 1);
  if (NT > 1) {
    stageA(1, 0); stageB(1, 1); stageA(1, 1);
    vwait_steady();
  } else {
    asm volatile("s_waitcnt vmcnt(0)" ::: "memory");
  }
  BARRIER();

  for (int t = 0; t < NT; ++t) {
    const int b = t & 1;
    readA(b, 0); readB(b, 0);
    if (t + 1 < NT) stageB(t + 1, 0);
    BARRIER(); LGKM0();
    __builtin_amdgcn_s_setprio(1); mf(0, 0); __builtin_amdgcn_s_setprio(0);
    BARRIER();
    readB(b, 1);
    if (t + 2 < NT) stageA(t + 2, 0);
    BARRIER(); LGKM0();
    __builtin_amdgcn_s_setprio(1); mf(0, 1); __builtin_amdgcn_s_setprio(0);
    BARRIER();
    readA(b, 1);
    if (t + 2 < NT) stageB(t + 2, 1);
    BARRIER(); LGKM0();
    __builtin_amdgcn_s_setprio(1); mf(1, 1); __builtin_amdgcn_s_setprio(0);
    BARRIER();
    readB(b, 0);
    if (t + 2 < NT) stageA(t + 2, 1);
    BARRIER(); LGKM0();
    __builtin_amdgcn_s_setprio(1); mf(1, 0); __builtin_amdgcn_s_setprio(0);
    if (t + 2 < NT) vwait_steady();
    else            asm volatile("s_waitcnt vmcnt(0)" ::: "memory");
    BARRIER();
  }

  const int rb = ((lane >> 4) & 3) * 4;
#pragma unroll
  for (int qa = 0; qa < 2; ++qa)
#pragma unroll
    for (int i = 0; i < 4; ++i)
#pragma unroll
      for (int qb = 0; qb < 2; ++qb)
#pragma unroll
        for (int j = 0; j < JT; ++j)
#pragma unroll
          for (int r = 0; r < 4; ++r)
            epi(wm * 128 + qa * 64 + i * 16 + rb + r,
                wn * CW + qb * QBS + j * 16 + ln,
                acc[qa * 4 + i][qb * JT + j][r]);
}

// y(bf16) = attn @ W_o^T + x    grid: 64m x 8n = 512 blocks
__global__ __launch_bounds__(512) void k_gemm_wo(const unsigned short* __restrict__ A,
                                                 const unsigned short* __restrict__ Bt,
                                                 const float* __restrict__ x,
                                                 unsigned short* __restrict__ y) {
  const int bid = blockIdx.x;
  const int swz = (bid & 7) * 64 + (bid >> 3);
  const int m0 = (swz >> 3) * 256, n0 = (swz & 7) * 256;
  gemm8p<256>(A + (size_t)m0 * 2048, Bt + (size_t)n0 * 2048, 2048, 2048, 2048,
              [=](int r, int cc, float v) {
                size_t idx = (size_t)(m0 + r) * 2048 + n0 + cc;
                y[idx] = f2b(v + x[idx]);
              });
}

// act = silu(h @ upW)   grid: 16m x 32n = 512 blocks
__global__ __launch_bounds__(512) void k_gemm_up2(const unsigned short* __restrict__ A,
                                                  const unsigned short* __restrict__ Bt,
                                                  unsigned short* __restrict__ act) {
  const int bid = blockIdx.x;
  const int swz = (bid & 7) * 64 + (bid >> 3);
  const int m0 = (swz >> 5) * 256, n0 = (swz & 31) * 256;
  gemm8p<256>(A + (size_t)m0 * 2048, Bt + (size_t)n0 * 2048, 2048, 2048, 2048,
              [=](int r, int cc, float v) {
                float s = v / (1.f + __expf(-v));
                act[(size_t)(m0 + r) * 8192 + n0 + cc] = f2b(s);
              });
}

// act *= (h @ gateW)   (RMW epilogue; act holds silu(up))
__global__ __launch_bounds__(512) void k_gemm_gatem(const unsigned short* __restrict__ A,
                                                    const unsigned short* __restrict__ Bt,
                                                    unsigned short* act) {
  const int bid = blockIdx.x;
  const int swz = (bid & 7) * 64 + (bid >> 3);
  const int m0 = (swz >> 5) * 256, n0 = (swz & 31) * 256;
  gemm8p<256>(A + (size_t)m0 * 2048, Bt + (size_t)n0 * 2048, 2048, 2048, 2048,
              [=](int r, int cc, float v) {
                size_t idx = (size_t)(m0 + r) * 8192 + n0 + cc;
                act[idx] = f2b(v * b2f(act[idx]));
              });
}

// outc(f32) = act @ downW^T + h   grid: 16m x 16n = 256 blocks (BN=128)
__global__ __launch_bounds__(512) void k_gemm_down2(const unsigned short* __restrict__ A,
                                                    const unsigned short* __restrict__ Bt,
                                                    const unsigned short* __restrict__ hbuf,
                                                    float* __restrict__ outc) {
  const int bid = blockIdx.x;
  const int swz = (bid & 7) * 32 + (bid >> 3);
  const int m0 = (swz >> 4) * 256, n0 = (swz & 15) * 128;
  gemm8p<128>(A + (size_t)m0 * 8192, Bt + (size_t)n0 * 8192, 8192, 8192, 8192,
              [=](int r, int cc, float v) {
                size_t idx = (size_t)(m0 + r) * 2048 + n0 + cc;
                outc[idx] = v + b2f(hbuf[idx]);
              });
}

// transpose+convert f32 [R][C] -> bf16 [C][R]
__global__ __launch_bounds__(256) void k_tc(const float* __restrict__ in,
                                            unsigned short* __restrict__ out, int R, int C) {
  __shared__ float tile[64][65];
  const int c0 = blockIdx.x * 64, r0 = blockIdx.y * 64;
  const int tid = threadIdx.x;
#pragma unroll
  for (int p = 0; p < 16; ++p) {
    int l = p * 256 + tid;
    int ir = l >> 6, ic = l & 63;
    tile[ic][ir] = in[(size_t)(r0 + ir) * C + c0 + ic];
  }
  __syncthreads();
#pragma unroll
  for (int p = 0; p < 16; ++p) {
    int l = p * 256 + tid;
    int oc = l >> 6, orr = l & 63;
    out[(size_t)(c0 + oc) * R + r0 + orr] = f2b(tile[oc][orr]);
  }
}

__global__ __launch_bounds__(256) void k_zero(float* __restrict__ p, int n) {
  int i = blockIdx.x * 256 + threadIdx.x;
  if (i < n) p[i] = 0.f;
}

// Wq_proj[h] = W_uq[:, h*128:+128] @ omega (f32); same for K-side.
__global__ __launch_bounds__(256) void k_wproj(const float* __restrict__ W_uq,
                                               const float* __restrict__ W_uk,
                                               const float* __restrict__ omega,
                                               float* __restrict__ wqp, float* __restrict__ wkp) {
  const int bi = blockIdx.x;
  const float* W;
  float* outp;
  int ldw, col0;
  if (bi < 16) { W = W_uq; outp = wqp + bi * 4096; ldw = 2048; col0 = bi * 128; }
  else         { W = W_uk; outp = wkp + (bi - 16) * 4096; ldw = 1024; col0 = (bi - 16) * 128; }
  __shared__ float om[128][64];
  const int tid = threadIdx.x;
#pragma unroll
  for (int p = 0; p < 32; ++p) {
    int l = p * 256 + tid;
    om[l >> 6][l & 63] = omega[l];
  }
  __syncthreads();
  const int r = tid >> 2, f0 = (tid & 3) * 16;
  float acc[16];
#pragma unroll
  for (int f = 0; f < 16; ++f) acc[f] = 0.f;
  const float* wrow = W + (size_t)r * ldw + col0;
  for (int d = 0; d < 128; ++d) {
    float w = wrow[d];
#pragma unroll
    for (int f = 0; f < 16; ++f) acc[f] += w * om[d][f0 + f];
  }
#pragma unroll
  for (int f = 0; f < 16; ++f) outp[r * 64 + f0 + f] = acc[f];
}

// c = x @ [W_dq | W_dkv], pure f32. Block: 64 tokens x 128 cols.
__global__ __launch_bounds__(256) void k_cgemm(const float* __restrict__ x,
                                               const float* __restrict__ W_dq,
                                               const float* __restrict__ W_dkv,
                                               float* __restrict__ cbuf) {
  __shared__ float xs[64][65];
  __shared__ float wsh[64][128];
  const int tok0 = blockIdx.x * 64;
  const int tid = threadIdx.x;
  const int ty = tid >> 3, tx = tid & 7;
  const int t0 = ty * 2, c0 = tx * 16;
  float acc[2][16];
#pragma unroll
  for (int i = 0; i < 2; ++i)
#pragma unroll
    for (int e = 0; e < 16; ++e) acc[i][e] = 0.f;
  for (int kb = 0; kb < 2048; kb += 64) {
#pragma unroll
    for (int p = 0; p < 16; ++p) {
      int l = p * 256 + tid;
      int tr = l >> 6, kd = l & 63;
      xs[tr][kd] = x[(size_t)(tok0 + tr) * 2048 + kb + kd];
    }
#pragma unroll
    for (int p = 0; p < 32; ++p) {
      int l = p * 256 + tid;
      int kd = l >> 7, c = l & 127;
      wsh[kd][c] = (c < 64) ? W_dq[(size_t)(kb + kd) * 64 + c]
                            : W_dkv[(size_t)(kb + kd) * 64 + (c - 64)];
    }
    __syncthreads();
    for (int kd = 0; kd < 64; ++kd) {
      float a0 = xs[t0][kd], a1 = xs[t0 + 1][kd];
#pragma unroll
      for (int e = 0; e < 16; ++e) {
        float w = wsh[kd][c0 + e];
        acc[0][e] += a0 * w;
        acc[1][e] += a1 * w;
      }
    }
    __syncthreads();
  }
#pragma unroll
  for (int i = 0; i < 2; ++i)
#pragma unroll
    for (int e = 0; e < 16; ++e)
      cbuf[(size_t)(tok0 + t0 + i) * 128 + c0 + e] = acc[i][e];
}

// phi_k (bf16, transposed [bh][f=128][s=4096]) + z accumulation (f32 atomicAdd).
__global__ __launch_bounds__(256) void k_phikz(const float* __restrict__ c,
                                               const float* __restrict__ wkp,
                                               unsigned short* __restrict__ phikT,
                                               float* __restrict__ z) {
  const int s0 = blockIdx.x * 64;
  const int bh = blockIdx.y;  // b*8+hkv
  const int b = bh >> 3, hkv = bh & 7;
  __shared__ float ck[64][65];
  __shared__ float wp[64][68];
  const int tid = threadIdx.x;
#pragma unroll
  for (int p = 0; p < 16; ++p) {
    int l = p * 256 + tid;
    int sr = l >> 6, d = l & 63;
    ck[sr][d] = c[(size_t)(b * 4096 + s0 + sr) * 128 + 64 + d];
    wp[sr][d] = wkp[hkv * 4096 + l];
  }
  __syncthreads();
  const int ty = tid & 31, fx = tid >> 5;
  const int f0 = fx * 8, r0 = ty * 2;
  float pr[2][8];
#pragma unroll
  for (int rr = 0; rr < 2; ++rr)
#pragma unroll
    for (int ff = 0; ff < 8; ++ff) pr[rr][ff] = 0.f;
  for (int d = 0; d < 64; ++d) {
    f32x4 w0 = *(const f32x4*)&wp[d][f0];
    f32x4 w1 = *(const f32x4*)&wp[d][f0 + 4];
    float c0v = ck[r0][d], c1v = ck[r0 + 1][d];
#pragma unroll
    for (int e = 0; e < 4; ++e) {
      pr[0][e] += c0v * w0[e]; pr[0][4 + e] += c0v * w1[e];
      pr[1][e] += c1v * w0[e]; pr[1][4 + e] += c1v * w1[e];
    }
  }
  unsigned short* obase = phikT + (size_t)bh * 524288 + s0 + r0;
  float zc[8], zs2[8];
#pragma unroll
  for (int ff = 0; ff < 8; ++ff) {
    float sv0, cv0, sv1, cv1;
    __sincosf(pr[0][ff], &sv0, &cv0);
    __sincosf(pr[1][ff], &sv1, &cv1);
    float c0 = cv0 * 0.125f, c1 = cv1 * 0.125f;
    float s0v = sv0 * 0.125f, s1v = sv1 * 0.125f;
    u16x2 co; co[0] = f2b(c0); co[1] = f2b(c1);
    u16x2 si; si[0] = f2b(s0v); si[1] = f2b(s1v);
    *(u16x2*)(obase + (size_t)(f0 + ff) * 4096) = co;
    *(u16x2*)(obase + (size_t)(64 + f0 + ff) * 4096) = si;
    zc[ff] = c0 + c1;
    zs2[ff] = s0v + s1v;
  }
#pragma unroll
  for (int off = 16; off; off >>= 1) {
#pragma unroll
    for (int ff = 0; ff < 8; ++ff) {
      zc[ff] += __shfl_down(zc[ff], off);
      zs2[ff] += __shfl_down(zs2[ff], off);
    }
  }
  if (ty == 0) {
#pragma unroll
    for (int ff = 0; ff < 8; ++ff) {
      atomicAdd(&z[bh * 128 + f0 + ff], zc[ff]);
      atomicAdd(&z[bh * 128 + 64 + f0 + ff], zs2[ff]);
    }
  }
}

// v = c_kv @ W_uv (bf16 out), transposed [bh][d=128][s=4096].
__global__ __launch_bounds__(256) void k_vf(const float* __restrict__ c,
                                            const float* __restrict__ W_uv,
                                            unsigned short* __restrict__ vT) {
  const int s0 = blockIdx.x * 64;
  const int bh = blockIdx.y;
  const int b = bh >> 3, hkv = bh & 7;
  __shared__ float ck[64][65];
  __shared__ float wv[64][132];
  const int tid = threadIdx.x;
#pragma unroll
  for (int p = 0; p < 16; ++p) {
    int l = p * 256 + tid;
    int sr = l >> 6, d = l & 63;
    ck[sr][d] = c[(size_t)(b * 4096 + s0 + sr) * 128 + 64 + d];
  }
#pragma unroll
  for (int p = 0; p < 32; ++p) {
    int l = p * 256 + tid;
    int rr = l >> 7, d = l & 127;
    wv[rr][d] = W_uv[(size_t)rr * 1024 + hkv * 128 + d];
  }
  __syncthreads();
  const int ty = tid & 15, tx = tid >> 4;
  const int r0 = ty * 4, d0 = tx * 8;
  float acc[4][8];
#pragma unroll
  for (int rr = 0; rr < 4; ++rr)
#pragma unroll
    for (int dd = 0; dd < 8; ++dd) acc[rr][dd] = 0.f;
  for (int kk = 0; kk < 64; ++kk) {
    f32x4 w0 = *(const f32x4*)&wv[kk][d0];
    f32x4 w1 = *(const f32x4*)&wv[kk][d0 + 4];
    float cv[4];
#pragma unroll
    for (int rr = 0; rr < 4; ++rr) cv[rr] = ck[r0 + rr][kk];
#pragma unroll
    for (int rr = 0; rr < 4; ++rr)
#pragma unroll
      for (int e = 0; e < 4; ++e) {
        acc[rr][e] += cv[rr] * w0[e];
        acc[rr][4 + e] += cv[rr] * w1[e];
      }
  }
  unsigned short* obase = vT + (size_t)bh * 524288 + s0 + r0;
#pragma unroll
  for (int dd = 0; dd < 8; ++dd) {
    u16x4 pv;
    pv[0] = f2b(acc[0][dd]); pv[1] = f2b(acc[1][dd]);
    pv[2] = f2b(acc[2][dd]); pv[3] = f2b(acc[3][dd]);
    *(u16x4*)(obase + (size_t)(d0 + dd) * 4096) = pv;
  }
}

// kv partials via MFMA: kvp[kc][bh][f][d] = phikT[f, kc*512:+512] @ vT[d, ...]^T
// grid (8 kchunks, 32 bh) = 256 blocks.
__global__ __launch_bounds__(256) void k_kvg(const unsigned short* __restrict__ phikT,
                                             const unsigned short* __restrict__ vT,
                                             float* __restrict__ kvp) {
  const int kc = blockIdx.x, bh = blockIdx.y;
  gemm_core(phikT + (size_t)bh * 524288 + kc * 512,
            vT + (size_t)bh * 524288 + kc * 512, 512, 4096, 4096,
            [=](int r, int cc, float v) {
              kvp[((size_t)(kc * 32 + bh) * 128 + r) * 128 + cc] = v;
            });
}

// reduce 8 kv partials + transpose -> kvbT[bhk][d=128][f=128] bf16.
// grid (2, 2, 32).
__global__ __launch_bounds__(256) void k_kvredt(const float* __restrict__ kvp,
                                                unsigned short* __restrict__ kvbT) {
  const int fx0 = blockIdx.x * 64, dx0 = blockIdx.y * 64, bhk = blockIdx.z;
  __shared__ float tile[64][65];
  const int tid = threadIdx.x;
#pragma unroll
  for (int p = 0; p < 16; ++p) {
    int l = p * 256 + tid;
    int fr = l >> 6, dc = l & 63;
    float s = 0.f;
#pragma unroll
    for (int kc = 0; kc < 8; ++kc)
      s += kvp[(size_t)kc * 524288 + ((size_t)bhk * 128 + fx0 + fr) * 128 + dx0 + dc];
    tile[dc][fr] = s;
  }
  __syncthreads();
#pragma unroll
  for (int p = 0; p < 16; ++p) {
    int l = p * 256 + tid;
    int dr = l >> 6, fc = l & 63;
    kvbT[((size_t)bhk * 128 + dx0 + dr) * 128 + fx0 + fc] = f2b(tile[dr][fc]);
  }
}

// phi_q (bf16 [bh][s][128]) + 1/den (f32 [bh][s]). grid (64 s-tiles, 64 bh).
// proj & den in full f32 (phase-sensitive: Cauchy-tailed omega).
__global__ __launch_bounds__(256) void k_phiq(const float* __restrict__ c,
                                              const float* __restrict__ wqp,
                                              const float* __restrict__ zb,
                                              unsigned short* __restrict__ phiq,
                                              float* __restrict__ rden) {
  const int s0 = blockIdx.x * 64;
  const int bh = blockIdx.y;            // b*16 + head
  const int b = bh >> 4, hh = bh & 15;
  const int bhk = (b << 3) + (hh >> 1);
  __shared__ float wq[4096];
  __shared__ float cqt[64][33];
  __shared__ float zl[128];
  const int tid = threadIdx.x;
  if (tid < 128) zl[tid] = zb[bhk * 128 + tid];
#pragma unroll
  for (int p = 0; p < 16; ++p) wq[p * 256 + tid] = wqp[hh * 4096 + p * 256 + tid];
  const int fx = tid & 7, ty = tid >> 3;
  const int f0 = fx * 8;
  for (int hf = 0; hf < 2; ++hf) {
    __syncthreads();
#pragma unroll
    for (int p = 0; p < 8; ++p) {
      int l = p * 256 + tid;
      int sr = l >> 6, dd = l & 63;
      cqt[dd][sr] = c[(size_t)(b * 4096 + s0 + hf * 32 + sr) * 128 + dd];
    }
    __syncthreads();
    float pr[8];
#pragma unroll
    for (int ff = 0; ff < 8; ++ff) pr[ff] = 0.f;
    for (int dd = 0; dd < 64; ++dd) {
      f32x4 w0 = *(const f32x4*)(wq + dd * 64 + f0);
      f32x4 w1 = *(const f32x4*)(wq + dd * 64 + f0 + 4);
      float cv = cqt[dd][ty];
#pragma unroll
      for (int e = 0; e < 4; ++e) { pr[e] += cv * w0[e]; pr[4 + e] += cv * w1[e]; }
    }
    float dpart = 0.f;
    u16x8 pc, ps;
#pragma unroll
    for (int ff = 0; ff < 8; ++ff) {
      float sv, cv;
      __sincosf(pr[ff], &sv, &cv);
      cv *= 0.125f; sv *= 0.125f;
      pc[ff] = f2b(cv); ps[ff] = f2b(sv);
      dpart += cv * zl[f0 + ff] + sv * zl[64 + f0 + ff];
    }
    unsigned short* ob = phiq + ((size_t)bh * 4096 + s0 + hf * 32 + ty) * 128;
    *(u16x8*)(ob + f0) = pc;
    *(u16x8*)(ob + 64 + f0) = ps;
    dpart += __shfl_down(dpart, 4);
    dpart += __shfl_down(dpart, 2);
    dpart += __shfl_down(dpart, 1);
    if (fx == 0) rden[(size_t)bh * 4096 + s0 + hf * 32 + ty] = 1.f / (dpart + 1e-6f);
  }
}

// num = phiq @ kvbT^T, scaled by 1/den -> attn bf16. grid (32 s-tiles, 64 bh).
__global__ __launch_bounds__(256) void k_num(const unsigned short* __restrict__ phiq,
                                             const unsigned short* __restrict__ kvbT,
                                             const float* __restrict__ rden,
                                             unsigned short* __restrict__ attn) {
  const int m0 = blockIdx.x * 128;
  const int bh = blockIdx.y;
  const int b = bh >> 4, hh = bh & 15;
  const int bhk = (b << 3) + (hh >> 1);
  const float* rd = rden + (size_t)bh * 4096 + m0;
  gemm_core(phiq + ((size_t)bh * 4096 + m0) * 128, kvbT + (size_t)bhk * 16384,
            128, 128, 128,
            [=](int r, int cc, float v) {
              attn[(size_t)(b * 4096 + m0 + r) * 2048 + hh * 128 + cc] = f2b(v * rd[r]);
            });
}

// LayerNorm bf16->bf16 (ln1)
__global__ __launch_bounds__(256) void k_ln_b2b(const unsigned short* __restrict__ in,
                                                const float* __restrict__ g,
                                                const float* __restrict__ bb,
                                                unsigned short* __restrict__ ob) {
  const int row = blockIdx.x;
  const unsigned short* xr = in + (size_t)row * 2048;
  float vals[8], s = 0.f, ss = 0.f;
#pragma unroll
  for (int i = 0; i < 8; ++i) {
    float v = b2f(xr[i * 256 + threadIdx.x]);
    vals[i] = v; s += v; ss += v * v;
  }
#pragma unroll
  for (int off = 32; off; off >>= 1) { s += __shfl_down(s, off); ss += __shfl_down(ss, off); }
  __shared__ float red[8];
  const int wave = threadIdx.x >> 6;
  if ((threadIdx.x & 63) == 0) { red[wave * 2] = s; red[wave * 2 + 1] = ss; }
  __syncthreads();
  float S = red[0] + red[2] + red[4] + red[6];
  float SS = red[1] + red[3] + red[5] + red[7];
  float mu = S * (1.f / 2048.f);
  float var = SS * (1.f / 2048.f) - mu * mu;
  float inv = rsqrtf(var + 1e-5f);
#pragma unroll
  for (int i = 0; i < 8; ++i) {
    int col = i * 256 + threadIdx.x;
    ob[(size_t)row * 2048 + col] = f2b((vals[i] - mu) * inv * g[col] + bb[col]);
  }
}

// In-place LayerNorm f32 (ln2 on out rows)
__global__ __launch_bounds__(256) void k_ln_ip(float* __restrict__ io,
                                               const float* __restrict__ g,
                                               const float* __restrict__ bb) {
  const int row = blockIdx.x;
  float* xr = io + (size_t)row * 2048;
  float vals[8], s = 0.f, ss = 0.f;
#pragma unroll
  for (int i = 0; i < 8; ++i) {
    float v = xr[i * 256 + threadIdx.x];
    vals[i] = v; s += v; ss += v * v;
  }
#pragma unroll
  for (int off = 32; off; off >>= 1) { s += __shfl_down(s, off); ss += __shfl_down(ss, off); }
  __shared__ float red[8];
  const int wave = threadIdx.x >> 6;
  if ((threadIdx.x & 63) == 0) { red[wave * 2] = s; red[wave * 2 + 1] = ss; }
  __syncthreads();
  float S = red[0] + red[2] + red[4] + red[6];
  float SS = red[1] + red[3] + red[5] + red[7];
  float mu = S * (1.f / 2048.f);
  float var = SS * (1.f / 2048.f) - mu * mu;
  float inv = rsqrtf(var + 1e-5f);
#pragma unroll
  for (int i = 0; i < 8; ++i) {
    int col = i * 256 + threadIdx.x;
    xr[col] = (vals[i] - mu) * inv * g[col] + bb[col];
  }
}

// ---------------------------------------------------------------------------
extern "C" void kernel_launch(void* const* d_in, const int* in_sizes, int n_in,
                              void* d_out, int out_size, void* d_ws, size_t ws_size,
                              hipStream_t stream) {
  (void)in_sizes; (void)n_in; (void)out_size; (void)ws_size;
  const float* x     = (const float*)d_in[0];
  const float* W_dq  = (const float*)d_in[1];
  const float* W_uq  = (const float*)d_in[2];
  const float* W_dkv = (const float*)d_in[3];
  const float* W_uk  = (const float*)d_in[4];
  const float* W_uv  = (const float*)d_in[5];
  const float* omega = (const float*)d_in[6];
  const float* W_o   = (const float*)d_in[7];
  const float* ln1g  = (const float*)d_in[8];
  const float* ln1b  = (const float*)d_in[9];
  const float* gateW = (const float*)d_in[10];
  const float* upW   = (const float*)d_in[11];
  const float* downW = (const float*)d_in[12];
  const float* ln2g  = (const float*)d_in[13];
  const float* ln2b  = (const float*)d_in[14];
  float* out = (float*)d_out;

  // Workspace (232 MiB, liveness-overlaid):
  // R0 [0,64M):    phikT(bf16,32M) -> phiq(bf16,64M) -> gatet|upt
  // R1 [64,128M):  vT(bf16,32M) -> attn(bf16,64M) -> hb(bf16)
  // R2 [128,192M): cbuf/wqp/wkp/zb/rden/kvbT/kvp -> y(bf16) -> act(64M)
  // R3 [192,200M): wot   R4 [200,232M): downt
  char* w = (char*)d_ws;
  unsigned short* phikT = (unsigned short*)(w);
  unsigned short* phiqb = (unsigned short*)(w);
  unsigned short* vT    = (unsigned short*)(w + 67108864);
  unsigned short* attn  = (unsigned short*)(w + 67108864);
  unsigned short* hb    = (unsigned short*)(w + 67108864);
  unsigned short* gatet = (unsigned short*)(w);
  unsigned short* upt   = (unsigned short*)(w + 33554432);
  char* C = w + 134217728;
  float*          cbuf = (float*)(C);
  float*          wqp  = (float*)(C + 8388608);
  float*          wkp  = (float*)(C + 8650752);
  float*          zb   = (float*)(C + 8781824);
  float*          rden = (float*)(C + 8798208);
  unsigned short* kvbT = (unsigned short*)(C + 9846784);
  float*          kvp  = (float*)(C + 10895360);
  unsigned short* y    = (unsigned short*)(C);
  unsigned short* act  = (unsigned short*)(C);
  unsigned short* wot   = (unsigned short*)(w + 201326592);
  unsigned short* downt = (unsigned short*)(w + 209715200);

  // phase 0: prep
  k_zero<<<16, 256, 0, stream>>>(zb, 4096);
  k_wproj<<<24, 256, 0, stream>>>(W_uq, W_uk, omega, wqp, wkp);
  k_tc<<<dim3(32, 32), 256, 0, stream>>>(W_o, wot, 2048, 2048);

  // phase 1: latents (f32)
  k_cgemm<<<256, 256, 0, stream>>>(x, W_dq, W_dkv, cbuf);

  // phase 2: phi_k + z, v (bf16 outputs)
  k_phikz<<<dim3(64, 32), 256, 0, stream>>>(cbuf, wkp, phikT, zb);
  k_vf<<<dim3(64, 32), 256, 0, stream>>>(cbuf, W_uv, vT);

  // phase 3: kv via MFMA (partials + reduce/transpose), phi_q, num via MFMA
  k_kvg<<<dim3(8, 32), 256, 0, stream>>>(phikT, vT, kvp);
  k_kvredt<<<dim3(2, 2, 32), 256, 0, stream>>>(kvp, kvbT);
  k_phiq<<<dim3(64, 64), 256, 0, stream>>>(cbuf, wqp, zb, phiqb, rden);
  k_num<<<dim3(32, 64), 256, 0, stream>>>(phiqb, kvbT, rden, attn);

  // phase 4: W_o + residual + LN1 (8-phase 256^2 GEMM)
  k_gemm_wo<<<dim3(512), 512, 0, stream>>>(attn, wot, x, y);
  k_ln_b2b<<<16384, 256, 0, stream>>>(y, ln1g, ln1b, hb);

  // phase 5: FFN weight transposes into freed regions
  k_tc<<<dim3(128, 32), 256, 0, stream>>>(gateW, gatet, 2048, 8192);
  k_tc<<<dim3(128, 32), 256, 0, stream>>>(upW, upt, 2048, 8192);
  k_tc<<<dim3(32, 128), 256, 0, stream>>>(downW, downt, 8192, 2048);

  // phase 6: FFN in 4 chunks of 4096 rows; no gate buffer, LN2 in-place on out
  for (int cix = 0; cix < 4; ++cix) {
    const unsigned short* hbc = hb + (size_t)cix * 4096 * 2048;
    float* outc = out + (size_t)cix * 4096 * 2048;
    k_gemm_up2<<<dim3(512), 512, 0, stream>>>(hbc, upt, act);
    k_gemm_gatem<<<dim3(512), 512, 0, stream>>>(hbc, gatet, act);
    k_gemm_down2<<<dim3(256), 512, 0, stream>>>(act, downt, hbc, outc);
    k_ln_ip<<<4096, 256, 0, stream>>>(outc, ln2g, ln2b);
  }
}